// Round 7
// baseline (193.100 us; speedup 1.0000x reference)
//
#include <hip/hip_runtime.h>
#include <hip/hip_cooperative_groups.h>
#include <cfloat>

namespace cg = cooperative_groups;

#define KK 5
#define BB 8
#define NN 200
#define DD 512
#define P2_UNITS 644
#define P3_UNITS 1568

// ---------------------------------------------------------------------------
// Shared phase bodies (used by both the cooperative kernel and the fallback)
// ---------------------------------------------------------------------------
__device__ __forceinline__ unsigned long long umin64(unsigned long long a,
                                                     unsigned long long b)
{ return b < a ? b : a; }

template <int C, int HW>
__device__ __forceinline__ void smap_body(
    const float* __restrict__ fmap, const float* __restrict__ lib,
    const int* __restrict__ idx, float* __restrict__ sm, int gid)
{
    if (gid >= KK * BB * HW) return;   // returns from THIS function only
    int px = gid % HW;
    int r  = gid / HW;
    int b  = r % BB;
    int k  = r / BB;
    int id = idx[b * KK + k];

    const float* f = fmap + (size_t)b  * C * HW + px;
    const float* l = lib  + (size_t)id * C * HW + px;

    float acc = 0.f;
#pragma unroll 16
    for (int c = 0; c < C; ++c) {
        float d = l[(size_t)c * HW] - f[(size_t)c * HW];
        acc = fmaf(d, d, acc);
    }
    sm[(size_t)(k * BB + b) * HW + px] = acc;
}

template <int S, int HW>
__device__ __forceinline__ float tap_min(const float* __restrict__ sm, int b,
                                         int yx)
{
    float m = FLT_MAX;
#pragma unroll
    for (int k = 0; k < KK; ++k)
        m = fminf(m, sm[(size_t)(k * BB + b) * HW + yx]);
    return m;
}

template <int S, int HW>
__device__ __forceinline__ float bil5(const float* __restrict__ sm, int b,
                                      int oy, int ox)
{
    const float scale = (float)S * (1.f / 224.f);
    float sy = fminf(fmaxf((oy + 0.5f) * scale - 0.5f, 0.f), (float)(S - 1));
    float sx = fminf(fmaxf((ox + 0.5f) * scale - 0.5f, 0.f), (float)(S - 1));
    int y0 = (int)sy, x0 = (int)sx;
    float ty = sy - y0, tx = sx - x0;
    int y1 = min(y0 + 1, S - 1), x1 = min(x0 + 1, S - 1);
    float v00 = tap_min<S, HW>(sm, b, y0 * S + x0);
    float v01 = tap_min<S, HW>(sm, b, y0 * S + x1);
    float v10 = tap_min<S, HW>(sm, b, y1 * S + x0);
    float v11 = tap_min<S, HW>(sm, b, y1 * S + x1);
    float top = v00 + tx * (v01 - v00);
    float bot = v10 + tx * (v11 - v10);
    return top + ty * (bot - top);
}

__device__ __forceinline__ void upsample_px(
    const float* __restrict__ sm0, const float* __restrict__ sm1,
    const float* __restrict__ sm2, float* __restrict__ out, int gid)
{
    int ox = gid % 224;
    int r  = gid / 224;
    int oy = r % 224;
    int b  = r / 224;
    float v = bil5<56, 3136>(sm0, b, oy, ox)
            + bil5<28,  784>(sm1, b, oy, ox)
            + bil5<14,  196>(sm2, b, oy, ox);
    out[BB + gid] = v;
}

// ---------------------------------------------------------------------------
// Cooperative single-dispatch kernel; all phases grid-stride so ANY grid
// size >= 16 blocks is correct (grid sized to co-residency at launch).
// ---------------------------------------------------------------------------
__global__ __launch_bounds__(256) void fused_kernel(
    const float* __restrict__ z, const float* __restrict__ zlib,
    const float* __restrict__ fmap0, const float* __restrict__ fmap1,
    const float* __restrict__ fmap2,
    const float* __restrict__ lib0, const float* __restrict__ lib1,
    const float* __restrict__ lib2,
    float* __restrict__ out,
    int* __restrict__ idx, float* __restrict__ sdist,
    float* __restrict__ sm0, float* __restrict__ sm1, float* __restrict__ sm2)
{
    cg::grid_group grid = cg::this_grid();
    const int blk  = blockIdx.x;
    const int tid  = threadIdx.x;
    const int gdim = gridDim.x;

    // ---------------- P1: s[b][n] = ||l_n||^2 - 2 z_b . l_n ----------------
    __shared__ float red[BB + 1][256];
    for (int n = blk; n < NN; n += gdim) {
        const float2 lv = ((const float2*)(zlib + (size_t)n * DD))[tid];
        red[0][tid] = lv.x * lv.x + lv.y * lv.y;
#pragma unroll
        for (int b = 0; b < BB; ++b) {
            float2 zv = ((const float2*)(z + b * DD))[tid];
            red[b + 1][tid] = lv.x * zv.x + lv.y * zv.y;
        }
        __syncthreads();
        for (int s = 128; s > 0; s >>= 1) {
            if (tid < s) {
#pragma unroll
                for (int j = 0; j < BB + 1; ++j)
                    red[j][tid] += red[j][tid + s];
            }
            __syncthreads();
        }
        if (tid < BB)
            sdist[tid * NN + n] = red[0][0] - 2.f * red[tid + 1][0];
        __syncthreads();
    }
    grid.sync();

    // ---------------- P1b: wave-level top-5 (packed u64 argmin) ------------
    if (blk < BB && tid < 64) {
        float zz = 0.f;
#pragma unroll
        for (int j = 0; j < 4; ++j) {
            float2 zv = ((const float2*)(z + blk * DD))[tid + 64 * j];
            zz += zv.x * zv.x + zv.y * zv.y;
        }
#pragma unroll
        for (int m = 32; m; m >>= 1) zz += __shfl_xor(zz, m);

        unsigned long long pk[4];
#pragma unroll
        for (int j = 0; j < 4; ++j) {
            int n = tid + 64 * j;
            float v = (n < NN) ? fmaxf(zz + sdist[blk * NN + n], 0.f) : FLT_MAX;
            pk[j] = ((unsigned long long)__float_as_uint(v) << 32) | (unsigned)n;
        }
        float sum = 0.f;
        for (int r = 0; r < KK; ++r) {
            unsigned long long p = umin64(umin64(pk[0], pk[1]),
                                          umin64(pk[2], pk[3]));
#pragma unroll
            for (int m = 32; m; m >>= 1)
                p = umin64(p, __shfl_xor(p, m));
            unsigned widx = (unsigned)(p & 0xFFFFFFFFu);
            sum += sqrtf(__uint_as_float((unsigned)(p >> 32)));
            if (tid == 0) idx[blk * KK + r] = (int)widx;
#pragma unroll
            for (int j = 0; j < 4; ++j)
                if ((unsigned)(pk[j] & 0xFFFFFFFFu) == widx)
                    pk[j] = 0xFFFFFFFFFFFFFFFFull;
        }
        if (tid == 0) out[blk] = sum * (1.f / KK);
    }
    grid.sync();

    // ---------------- P2: smap planes ----------------
    for (int u = blk; u < P2_UNITS; u += gdim) {
        if (u < 490) {
            smap_body<64, 3136>(fmap0, lib0, idx, sm0, u * 256 + tid);
        } else if (u < 613) {
            smap_body<128, 784>(fmap1, lib1, idx, sm1, (u - 490) * 256 + tid);
        } else {
            smap_body<256, 196>(fmap2, lib2, idx, sm2, (u - 613) * 256 + tid);
        }
    }
    grid.sync();

    // ---------------- P3: min-over-k + bilinear + 3-scale sum --------------
    for (int w = blk; w < P3_UNITS; w += gdim)
        upsample_px(sm0, sm1, sm2, out, w * 256 + tid);
}

// ---------------------------------------------------------------------------
// Fallback kernels (proven round-5 path) in case cooperative launch fails.
// ---------------------------------------------------------------------------
__global__ __launch_bounds__(256) void topk_kernel(
    const float* __restrict__ z, const float* __restrict__ zlib,
    float* __restrict__ zscore, int* __restrict__ idx_out)
{
    int b   = blockIdx.x;
    int tid = threadIdx.x;

    __shared__ float4 zs4[DD / 4];
    __shared__ float  dist[NN];
    if (tid < DD / 4)
        zs4[tid] = ((const float4*)(z + b * DD))[tid];
    __syncthreads();

    for (int n = tid; n < NN; n += 256) {
        const float4* lrow = (const float4*)(zlib + (size_t)n * DD);
        float zz = 0.f, ll = 0.f, dot = 0.f;
#pragma unroll 8
        for (int c = 0; c < DD / 4; ++c) {
            float4 a = zs4[c];
            float4 l = lrow[c];
            zz  = fmaf(a.x, a.x, fmaf(a.y, a.y, fmaf(a.z, a.z, fmaf(a.w, a.w, zz))));
            ll  = fmaf(l.x, l.x, fmaf(l.y, l.y, fmaf(l.z, l.z, fmaf(l.w, l.w, ll))));
            dot = fmaf(a.x, l.x, fmaf(a.y, l.y, fmaf(a.z, l.z, fmaf(a.w, l.w, dot))));
        }
        float d2 = zz + ll - 2.f * dot;
        dist[n] = sqrtf(fmaxf(d2, 0.f));
    }
    __syncthreads();

    __shared__ float sval[256];
    __shared__ int   sidx[256];
    float sum = 0.f;
    for (int it = 0; it < KK; ++it) {
        sval[tid] = (tid < NN) ? dist[tid] : FLT_MAX;
        sidx[tid] = tid;
        __syncthreads();
        for (int s = 128; s > 0; s >>= 1) {
            if (tid < s) {
                float v2 = sval[tid + s]; int i2 = sidx[tid + s];
                if (v2 < sval[tid] || (v2 == sval[tid] && i2 < sidx[tid])) {
                    sval[tid] = v2; sidx[tid] = i2;
                }
            }
            __syncthreads();
        }
        if (tid == 0) {
            int sel = sidx[0];
            idx_out[b * KK + it] = sel;
            sum += sval[0];
            dist[sel] = FLT_MAX;
        }
        __syncthreads();
    }
    if (tid == 0) zscore[b] = sum * (1.f / KK);
}

__global__ __launch_bounds__(256) void smap_kernel(
    const float* __restrict__ fmap0, const float* __restrict__ fmap1,
    const float* __restrict__ fmap2,
    const float* __restrict__ lib0, const float* __restrict__ lib1,
    const float* __restrict__ lib2,
    const int* __restrict__ idx,
    float* __restrict__ sm0, float* __restrict__ sm1, float* __restrict__ sm2,
    int nb0, int nb1)
{
    int blk = blockIdx.x;
    if (blk < nb0) {
        smap_body<64, 3136>(fmap0, lib0, idx, sm0, blk * 256 + threadIdx.x);
    } else if (blk < nb0 + nb1) {
        smap_body<128, 784>(fmap1, lib1, idx, sm1, (blk - nb0) * 256 + threadIdx.x);
    } else {
        smap_body<256, 196>(fmap2, lib2, idx, sm2, (blk - nb0 - nb1) * 256 + threadIdx.x);
    }
}

__global__ __launch_bounds__(256) void upsample_kernel(
    const float* __restrict__ sm0, const float* __restrict__ sm1,
    const float* __restrict__ sm2, float* __restrict__ out)
{
    int gid = blockIdx.x * 256 + threadIdx.x;
    if (gid >= BB * 224 * 224) return;
    upsample_px(sm0, sm1, sm2, out, gid);
}

// ---------------------------------------------------------------------------
extern "C" void kernel_launch(void* const* d_in, const int* in_sizes, int n_in,
                              void* d_out, int out_size, void* d_ws, size_t ws_size,
                              hipStream_t stream)
{
    const float* z     = (const float*)d_in[0];
    const float* zlib  = (const float*)d_in[1];
    const float* fmap0 = (const float*)d_in[2];
    const float* fmap1 = (const float*)d_in[3];
    const float* fmap2 = (const float*)d_in[4];
    const float* lib0  = (const float*)d_in[5];
    const float* lib1  = (const float*)d_in[6];
    const float* lib2  = (const float*)d_in[7];
    float* out = (float*)d_out;

    char* ws = (char*)d_ws;
    int*   idx   = (int*)ws;                        // 40 ints
    float* sdist = (float*)(ws + 256);              // 8*200 floats
    float* sm0   = sdist + BB * NN;                 // 5*8*3136
    float* sm1   = sm0 + (size_t)KK * BB * 3136;    // 5*8*784
    float* sm2   = sm1 + (size_t)KK * BB * 784;     // 5*8*196

    // Size cooperative grid to guaranteed co-residency (host queries only —
    // graph-capture-safe, deterministic).
    int dev = 0;
    (void)hipGetDevice(&dev);
    int cus = 0;
    (void)hipDeviceGetAttribute(&cus, hipDeviceAttributeMultiprocessorCount, dev);
    int maxBlocksPerCU = 0;
    (void)hipOccupancyMaxActiveBlocksPerMultiprocessor(
        &maxBlocksPerCU, (const void*)fused_kernel, 256, 0);
    long cap = (long)maxBlocksPerCU * (long)cus;
    int grid = (int)(cap < P2_UNITS ? cap : P2_UNITS);

    hipError_t err = hipErrorUnknown;
    if (grid >= 16) {
        void* args[] = {
            (void*)&z, (void*)&zlib,
            (void*)&fmap0, (void*)&fmap1, (void*)&fmap2,
            (void*)&lib0, (void*)&lib1, (void*)&lib2,
            (void*)&out, (void*)&idx, (void*)&sdist,
            (void*)&sm0, (void*)&sm1, (void*)&sm2,
        };
        err = hipLaunchCooperativeKernel((void*)fused_kernel, dim3(grid),
                                         dim3(256), args, 0, stream);
    }
    if (err != hipSuccess) {
        // Fallback: proven 3-kernel path.
        topk_kernel<<<BB, 256, 0, stream>>>(z, zlib, out, idx);
        smap_kernel<<<P2_UNITS, 256, 0, stream>>>(fmap0, fmap1, fmap2,
                                                  lib0, lib1, lib2,
                                                  idx, sm0, sm1, sm2, 490, 123);
        upsample_kernel<<<P3_UNITS, 256, 0, stream>>>(sm0, sm1, sm2, out);
    }
}

// Round 8
// 46.340 us; speedup vs baseline: 4.1670x; 4.1670x over previous
//
#include <hip/hip_runtime.h>
#include <cfloat>

#define KK 5
#define BB 8
#define NN 200
#define DD 512

// ---------------------------------------------------------------------------
// Kernel A: per-batch distances + top-5 (smallest) + z_score + minmap init.
// One block per batch; thread-per-row dot products with float4 row loads
// (zlib is L2-resident after first touch; 128 load instrs/thread). Then a
// 5-round block-tree argmin (value, lowest index on ties — matches
// jax.lax.top_k selection set). Also re-inits the minmaps to +INF every call
// (ws is NOT re-poisoned between replays; atomicMin needs a known start).
// ---------------------------------------------------------------------------
__global__ __launch_bounds__(256) void topk_kernel(
    const float* __restrict__ z, const float* __restrict__ zlib,
    float* __restrict__ zscore, int* __restrict__ idx_out,
    unsigned* __restrict__ minmaps, int mm_total)
{
    int b   = blockIdx.x;   // 0..7
    int tid = threadIdx.x;  // 0..255

    // init all min-maps to +inf (0x7F800000): 8*256 threads cover 32928 words
    for (int i = b * 256 + tid; i < mm_total; i += BB * 256)
        minmaps[i] = 0x7F800000u;

    __shared__ float4 zs4[DD / 4];   // 128 float4
    __shared__ float  dist[NN];
    if (tid < DD / 4)
        zs4[tid] = ((const float4*)(z + b * DD))[tid];
    __syncthreads();

    for (int n = tid; n < NN; n += 256) {
        const float4* lrow = (const float4*)(zlib + (size_t)n * DD);
        float zz = 0.f, ll = 0.f, dot = 0.f;
#pragma unroll 8
        for (int c = 0; c < DD / 4; ++c) {
            float4 a = zs4[c];
            float4 l = lrow[c];
            zz  = fmaf(a.x, a.x, fmaf(a.y, a.y, fmaf(a.z, a.z, fmaf(a.w, a.w, zz))));
            ll  = fmaf(l.x, l.x, fmaf(l.y, l.y, fmaf(l.z, l.z, fmaf(l.w, l.w, ll))));
            dot = fmaf(a.x, l.x, fmaf(a.y, l.y, fmaf(a.z, l.z, fmaf(a.w, l.w, dot))));
        }
        float d2 = zz + ll - 2.f * dot;
        dist[n] = sqrtf(fmaxf(d2, 0.f));
    }
    __syncthreads();

    __shared__ float sval[256];
    __shared__ int   sidx[256];
    float sum = 0.f;
    for (int it = 0; it < KK; ++it) {
        sval[tid] = (tid < NN) ? dist[tid] : FLT_MAX;
        sidx[tid] = tid;
        __syncthreads();
        for (int s = 128; s > 0; s >>= 1) {
            if (tid < s) {
                float v2 = sval[tid + s]; int i2 = sidx[tid + s];
                if (v2 < sval[tid] || (v2 == sval[tid] && i2 < sidx[tid])) {
                    sval[tid] = v2; sidx[tid] = i2;
                }
            }
            __syncthreads();
        }
        if (tid == 0) {
            int sel = sidx[0];
            idx_out[b * KK + it] = sel;
            sum += sval[0];
            dist[sel] = FLT_MAX;   // exclude for next round
        }
        __syncthreads();
    }
    if (tid == 0) zscore[b] = sum * (1.f / KK);
}

// ---------------------------------------------------------------------------
// Kernel B: thread per (k,b,pixel); sum over channels of squared diff,
// atomicMin into per-scale min-map (float-as-uint is order-preserving for
// non-negative). 644 blocks / 2576 waves -> all 256 CUs engaged; scalar
// loads perfectly coalesced (consecutive lanes -> consecutive pixels).
// FETCH_SIZE measured at the algorithmic minimum (~52 MB) in this shape.
// ---------------------------------------------------------------------------
template <int C, int HW>
__device__ __forceinline__ void smap_body(
    const float* __restrict__ fmap, const float* __restrict__ lib,
    const int* __restrict__ idx, unsigned* __restrict__ mm, int gid)
{
    if (gid >= KK * BB * HW) return;
    int px = gid % HW;
    int r  = gid / HW;
    int b  = r % BB;
    int k  = r / BB;
    int id = idx[b * KK + k];

    const float* f = fmap + (size_t)b  * C * HW + px;
    const float* l = lib  + (size_t)id * C * HW + px;

    float acc = 0.f;
#pragma unroll 16
    for (int c = 0; c < C; ++c) {
        float d = l[(size_t)c * HW] - f[(size_t)c * HW];
        acc = fmaf(d, d, acc);
    }
    atomicMin(&mm[b * HW + px], __float_as_uint(acc));
}

__global__ __launch_bounds__(256) void smap_kernel(
    const float* __restrict__ fmap0, const float* __restrict__ fmap1,
    const float* __restrict__ fmap2,
    const float* __restrict__ lib0, const float* __restrict__ lib1,
    const float* __restrict__ lib2,
    const int* __restrict__ idx,
    unsigned* __restrict__ mm0, unsigned* __restrict__ mm1,
    unsigned* __restrict__ mm2,
    int nb0, int nb1)
{
    int blk = blockIdx.x;
    if (blk < nb0) {
        smap_body<64, 3136>(fmap0, lib0, idx, mm0, blk * 256 + threadIdx.x);
    } else if (blk < nb0 + nb1) {
        smap_body<128, 784>(fmap1, lib1, idx, mm1, (blk - nb0) * 256 + threadIdx.x);
    } else {
        smap_body<256, 196>(fmap2, lib2, idx, mm2, (blk - nb0 - nb1) * 256 + threadIdx.x);
    }
}

// ---------------------------------------------------------------------------
// Kernel C: bilinear upsample (half-pixel, edge-clamped == jax.image.resize
// "bilinear" for pure upsampling) of the 3 min-maps (132 KB, L2-resident),
// summed. 12 taps per output pixel.
// ---------------------------------------------------------------------------
__device__ __forceinline__ float bil(const unsigned* __restrict__ m, int S,
                                     int oy, int ox)
{
    float scale = (float)S * (1.f / 224.f);
    float sy = fminf(fmaxf((oy + 0.5f) * scale - 0.5f, 0.f), (float)(S - 1));
    float sx = fminf(fmaxf((ox + 0.5f) * scale - 0.5f, 0.f), (float)(S - 1));
    int y0 = (int)sy, x0 = (int)sx;
    float ty = sy - y0, tx = sx - x0;
    int y1 = min(y0 + 1, S - 1), x1 = min(x0 + 1, S - 1);
    float v00 = __uint_as_float(m[y0 * S + x0]);
    float v01 = __uint_as_float(m[y0 * S + x1]);
    float v10 = __uint_as_float(m[y1 * S + x0]);
    float v11 = __uint_as_float(m[y1 * S + x1]);
    float top = v00 + tx * (v01 - v00);
    float bot = v10 + tx * (v11 - v10);
    return top + ty * (bot - top);
}

__global__ __launch_bounds__(256) void upsample_kernel(
    const unsigned* __restrict__ mm0, const unsigned* __restrict__ mm1,
    const unsigned* __restrict__ mm2, float* __restrict__ out)
{
    int gid = blockIdx.x * 256 + threadIdx.x;   // over 8*224*224
    if (gid >= BB * 224 * 224) return;
    int ox = gid % 224;
    int r  = gid / 224;
    int oy = r % 224;
    int b  = r / 224;

    float v = bil(mm0 + b * 3136, 56, oy, ox)
            + bil(mm1 + b * 784,  28, oy, ox)
            + bil(mm2 + b * 196,  14, oy, ox);
    out[BB + gid] = v;   // first 8 floats are z_score
}

// ---------------------------------------------------------------------------
extern "C" void kernel_launch(void* const* d_in, const int* in_sizes, int n_in,
                              void* d_out, int out_size, void* d_ws, size_t ws_size,
                              hipStream_t stream)
{
    const float* z     = (const float*)d_in[0];
    const float* zlib  = (const float*)d_in[1];
    const float* fmap0 = (const float*)d_in[2];
    const float* fmap1 = (const float*)d_in[3];
    const float* fmap2 = (const float*)d_in[4];
    const float* lib0  = (const float*)d_in[5];
    const float* lib1  = (const float*)d_in[6];
    const float* lib2  = (const float*)d_in[7];
    float* out = (float*)d_out;

    char* ws = (char*)d_ws;
    int*      idx = (int*)ws;                      // 40 ints
    unsigned* mm0 = (unsigned*)(ws + 256);         // 8*3136
    unsigned* mm1 = mm0 + BB * 3136;               // 8*784
    unsigned* mm2 = mm1 + BB * 784;                // 8*196
    const int mm_total = BB * (3136 + 784 + 196);  // 32928

    topk_kernel<<<BB, 256, 0, stream>>>(z, zlib, out, idx, mm0, mm_total);

    // blocks: scale0: 5*8*3136/256 = 490; scale1: ceil(31360/256) = 123;
    // scale2: ceil(7840/256) = 31  => 644 blocks
    smap_kernel<<<644, 256, 0, stream>>>(fmap0, fmap1, fmap2,
                                         lib0, lib1, lib2,
                                         idx, mm0, mm1, mm2, 490, 123);

    upsample_kernel<<<1568, 256, 0, stream>>>(mm0, mm1, mm2, out);
}